// Round 10
// baseline (292.698 us; speedup 1.0000x reference)
//
#include <hip/hip_runtime.h>
#include <math.h>

// Problem constants (fixed by the reference file)
#define NND 100000            // nodes
#define NED 1600000           // edges (before self-loops)
#define TOTE (NND + NED)      // edges + self-loops

#define SCAN_BS 256
#define SCAN_NB ((NND + SCAN_BS - 1) / SCAN_BS)   // 391

// dst-range-partitioned scatter (one range per XCD)
#define NRANGE 8
#define RNG_NODES ((NND + NRANGE - 1) / NRANGE)   // 12500
#define NCHUNK 640
#define CHUNK_E ((NED + NCHUNK - 1) / NCHUNK)     // 2500

// Workspace layout (bytes), total ~90.9 MB
#define OFF_HB    ((size_t)0)            // N*128 bf16 (h)
#define OFF_YS    ((size_t)25600000)     // N*128 bf16 (relu(agg+bias)) -- was f32
#define OFF_ASRC  ((size_t)76800000)
#define OFF_ADST  ((size_t)78400000)
#define OFF_OFFS  ((size_t)80000000)
#define OFF_CNT   ((size_t)80400016)
#define OFF_SRT   ((size_t)80800016)
#define OFF_BSUM  ((size_t)87600016)
#define OFF_BPREF ((size_t)87604016)
#define OFF_WF    ((size_t)87608016)     // 3072 frags * 8 ushort = 48 KB
#define OFF_M4    ((size_t)87657168)     // N*4 f32 (segment max)
#define OFF_INV4  ((size_t)89257168)     // N*4 f32 (1/denom)

typedef __attribute__((ext_vector_type(8))) short short8;
typedef __attribute__((ext_vector_type(4))) float f32x4;

__device__ __forceinline__ float leaky02(float v) { return v > 0.f ? v : 0.2f * v; }

// f32 -> bf16 with round-to-nearest-even
__device__ __forceinline__ unsigned short f2bf(float f) {
    unsigned u = __float_as_uint(f);
    return (unsigned short)((u + 0x7fffu + ((u >> 16) & 1u)) >> 16);
}

// ---------------------------------------------------------------------------
// CSR build (all proven r6-r8, frozen)
// ---------------------------------------------------------------------------
__global__ __launch_bounds__(256)
void k_count_init(int* __restrict__ counts) {
    const int i = blockIdx.x * 256 + threadIdx.x;
    if (i < NND) counts[i] = 1;
}

__global__ __launch_bounds__(256)
void k_hist(const int* __restrict__ edst, int* __restrict__ counts) {
    const int e = blockIdx.x * 256 + threadIdx.x;
    if (e < NED) atomicAdd(&counts[edst[e]], 1);
}

__global__ __launch_bounds__(SCAN_BS)
void k_scan_partial(const int* __restrict__ counts, int* __restrict__ bsum) {
    __shared__ int s[SCAN_BS];
    const int t = threadIdx.x;
    const int i = blockIdx.x * SCAN_BS + t;
    s[t] = (i < NND) ? counts[i] : 0;
    __syncthreads();
#pragma unroll
    for (int d = SCAN_BS / 2; d > 0; d >>= 1) {
        if (t < d) s[t] += s[t + d];
        __syncthreads();
    }
    if (t == 0) bsum[blockIdx.x] = s[0];
}

__global__ __launch_bounds__(512)
void k_scan_bsums(const int* __restrict__ bsum, int* __restrict__ bpref) {
    __shared__ int s[512];
    const int t = threadIdx.x;
    const int v0 = (t < SCAN_NB) ? bsum[t] : 0;
    s[t] = v0;
    __syncthreads();
#pragma unroll
    for (int d = 1; d < 512; d <<= 1) {
        int v = (t >= d) ? s[t - d] : 0;
        __syncthreads();
        s[t] += v;
        __syncthreads();
    }
    if (t < SCAN_NB) bpref[t] = s[t] - v0;   // exclusive
}

__global__ __launch_bounds__(SCAN_BS)
void k_scan_final(const int* __restrict__ counts, const int* __restrict__ bpref,
                  int* __restrict__ off) {
    __shared__ int s[SCAN_BS];
    const int t = threadIdx.x;
    const int i = blockIdx.x * SCAN_BS + t;
    const int v0 = (i < NND) ? counts[i] : 0;
    s[t] = v0;
    __syncthreads();
#pragma unroll
    for (int d = 1; d < SCAN_BS; d <<= 1) {
        int v = (t >= d) ? s[t - d] : 0;
        __syncthreads();
        s[t] += v;
        __syncthreads();
    }
    if (i < NND) off[i + 1] = bpref[blockIdx.x] + s[t];
    if (i == 0) off[0] = 0;
}

// Range-partitioned scatter (r8 proven).
__global__ __launch_bounds__(256)
void k_scatter_rng(const int* __restrict__ esrc, const int* __restrict__ edst,
                   const int* __restrict__ off, int* __restrict__ counts,
                   int* __restrict__ ssrt)
{
    const int r = blockIdx.x % NRANGE;
    const int chunk = blockIdx.x / NRANGE;
    const int dlo = r * RNG_NODES;
    const int dhi = min(NND, dlo + RNG_NODES);

    if (chunk == 0) {
        for (int d = dlo + threadIdx.x; d < dhi; d += 256)
            ssrt[off[d]] = d;
    }
    const int elo = chunk * CHUNK_E;
    const int ehi = min(NED, elo + CHUNK_E);
    for (int e = elo + threadIdx.x; e < ehi; e += 256) {
        const int d = edst[e];
        if (d >= dlo && d < dhi) {
            const int pos = off[d] + atomicAdd(&counts[d], 1);
            ssrt[pos] = esrc[e];
        }
    }
}

// ---------------------------------------------------------------------------
// W pre-fragmentation (r9 proven, extended with lin_w fragments for k_out).
// idx<2048: W frags  id=((wv*2+ct)*4+ks)*64+l, elem j:
//   B[k=ks*32+(l>>4)*8+j][col=wv*32+ct*16+(l&15)]
// idx in [2048,3072): lin_w frags  id2=(wv*4+ks)*64+l, elem j:
//   B[k=ks*32+(l>>4)*8+j][col=wv*16+(l&15)]   (lin_w is [128][64])
// ---------------------------------------------------------------------------
__global__ __launch_bounds__(256)
void k_wprep(const float* __restrict__ W, const float* __restrict__ lin_w,
             unsigned short* __restrict__ wf) {
    const int idx = blockIdx.x * 256 + threadIdx.x;
    if (idx < 2048) {
        const int l  = idx & 63;
        const int ks = (idx >> 6) & 3;
        const int ct = (idx >> 8) & 1;
        const int wv = idx >> 9;
        const int col = wv * 32 + ct * 16 + (l & 15);
        const int k0  = ks * 32 + (l >> 4) * 8;
#pragma unroll
        for (int j = 0; j < 8; ++j)
            wf[idx * 8 + j] = f2bf(W[(size_t)(k0 + j) * 128 + col]);
    } else if (idx < 3072) {
        const int i2 = idx - 2048;
        const int l  = i2 & 63;
        const int ks = (i2 >> 6) & 3;
        const int wv = i2 >> 8;
        const int col = wv * 16 + (l & 15);
        const int k0  = ks * 32 + (l >> 4) * 8;
#pragma unroll
        for (int j = 0; j < 8; ++j)
            wf[idx * 8 + j] = f2bf(lin_w[(size_t)(k0 + j) * 64 + col]);
    }
}

// ---------------------------------------------------------------------------
// K1 (MFMA): h = x @ W (bf16 out), fused a_src/a_dst epilogue. (r9 proven.)
// ---------------------------------------------------------------------------
__global__ __launch_bounds__(256)
void k_gemm1(const float* __restrict__ x, const unsigned short* __restrict__ wf,
             const float* __restrict__ att_s, const float* __restrict__ att_d,
             unsigned short* __restrict__ hb,
             float* __restrict__ a_src, float* __restrict__ a_dst)
{
    __shared__ unsigned short xb[32 * 128];   // 8 KB, XOR-swizzled
    const int tid = threadIdx.x;
    const int wv = tid >> 6;          // wave = head
    const int l = tid & 63;
    const int lg = l >> 4;
    const int lc = l & 15;
    const int row0 = blockIdx.x * 32;

    const float4* x4 = (const float4*)(x + (size_t)row0 * 128);
#pragma unroll
    for (int i = 0; i < 4; ++i) {
        const int g = tid + 256 * i;
        const int row = g >> 5;
        const int kq = g & 31;
        const float4 v = x4[g];
        uint2 p;
        p.x = (unsigned)f2bf(v.x) | ((unsigned)f2bf(v.y) << 16);
        p.y = (unsigned)f2bf(v.z) | ((unsigned)f2bf(v.w) << 16);
        const int byteoff = (row * 256 + kq * 8) ^ ((row & 7) << 4);
        *(uint2*)((char*)xb + byteoff) = p;
    }

    short8 bf[2][4];
#pragma unroll
    for (int ct = 0; ct < 2; ++ct)
#pragma unroll
        for (int ks = 0; ks < 4; ++ks)
            bf[ct][ks] = *(const short8*)(wf + (size_t)((((wv * 2 + ct) * 4 + ks) * 64 + l) * 8));

    __syncthreads();

    f32x4 acc[2][2];
#pragma unroll
    for (int rt = 0; rt < 2; ++rt)
#pragma unroll
        for (int ct = 0; ct < 2; ++ct)
            acc[rt][ct] = (f32x4){0.f, 0.f, 0.f, 0.f};

#pragma unroll
    for (int ks = 0; ks < 4; ++ks) {
        short8 a[2];
#pragma unroll
        for (int rt = 0; rt < 2; ++rt) {
            const int row = rt * 16 + lc;
            const int byteoff = (row * 256 + (ks * 32 + lg * 8) * 2) ^ ((row & 7) << 4);
            a[rt] = *(const short8*)((const char*)xb + byteoff);
        }
#pragma unroll
        for (int rt = 0; rt < 2; ++rt)
#pragma unroll
            for (int ct = 0; ct < 2; ++ct)
                acc[rt][ct] = __builtin_amdgcn_mfma_f32_16x16x32_bf16(
                    a[rt], bf[ct][ks], acc[rt][ct], 0, 0, 0);
    }

    const int c0 = wv * 32 + lc;
    const float as0 = att_s[c0], as1 = att_s[c0 + 16];
    const float ad0 = att_d[c0], ad1 = att_d[c0 + 16];

#pragma unroll
    for (int rt = 0; rt < 2; ++rt) {
#pragma unroll
        for (int r = 0; r < 4; ++r) {
            const int row = row0 + rt * 16 + lg * 4 + r;
            const float h0 = acc[rt][0][r];
            const float h1 = acc[rt][1][r];
            hb[(size_t)row * 128 + c0]      = f2bf(h0);
            hb[(size_t)row * 128 + c0 + 16] = f2bf(h1);
            float vs = h0 * as0 + h1 * as1;
            float vd = h0 * ad0 + h1 * ad1;
#pragma unroll
            for (int o = 8; o > 0; o >>= 1) {
                vs += __shfl_xor(vs, o, 64);
                vd += __shfl_xor(vd, o, 64);
            }
            if (lc == 0) {
                a_src[row * 4 + wv] = vs;
                a_dst[row * 4 + wv] = vd;
            }
        }
    }
}

// ---------------------------------------------------------------------------
// K_prep: per-node segment max + inv-denom, one THREAD per node, serial over
// its edges, all 4 heads in registers. No shuffles, no idle lanes -- replaces
// the two 6-step x 4-comp butterflies (~96 wave-instr/node) in k_fused.
// ---------------------------------------------------------------------------
__global__ __launch_bounds__(256)
void k_prep(const int* __restrict__ off, const int* __restrict__ ssrt,
            const float* __restrict__ a_src, const float* __restrict__ a_dst,
            float* __restrict__ m4, float* __restrict__ inv4)
{
    const int d = blockIdx.x * 256 + threadIdx.x;
    if (d >= NND) return;
    const int beg = off[d];
    const int end = off[d + 1];
    const float4 ad = *(const float4*)(a_dst + (size_t)d * 4);

    float4 mx = make_float4(-1e30f, -1e30f, -1e30f, -1e30f);
    for (int i = beg; i < end; ++i) {
        const int s = ssrt[i];
        const float4 as = *(const float4*)(a_src + (size_t)s * 4);
        mx.x = fmaxf(mx.x, leaky02(as.x + ad.x));
        mx.y = fmaxf(mx.y, leaky02(as.y + ad.y));
        mx.z = fmaxf(mx.z, leaky02(as.z + ad.z));
        mx.w = fmaxf(mx.w, leaky02(as.w + ad.w));
    }
    float4 sm = make_float4(0.f, 0.f, 0.f, 0.f);
    for (int i = beg; i < end; ++i) {
        const int s = ssrt[i];
        const float4 as = *(const float4*)(a_src + (size_t)s * 4);
        sm.x += __expf(leaky02(as.x + ad.x) - mx.x);
        sm.y += __expf(leaky02(as.y + ad.y) - mx.y);
        sm.z += __expf(leaky02(as.z + ad.z) - mx.z);
        sm.w += __expf(leaky02(as.w + ad.w) - mx.w);
    }
    *(float4*)(m4 + (size_t)d * 4) = mx;
    *(float4*)(inv4 + (size_t)d * 4) =
        make_float4(1.f / (sm.x + 1e-16f), 1.f / (sm.y + 1e-16f),
                    1.f / (sm.z + 1e-16f), 1.f / (sm.w + 1e-16f));
}

// ---------------------------------------------------------------------------
// K_fused (reduction-free): per-node wave computes alphas (m/inv precomputed),
// stages src/alpha in per-wave LDS, gathers bf16 h rows with a wave-uniform
// SGPR base (readfirstlane: src is identical across lanes -> scalar address
// math, loop-invariant voffset). Epilogue: bias+relu, bf16 ys out.
// ---------------------------------------------------------------------------
__global__ __launch_bounds__(256)
void k_fused(const int* __restrict__ off, const int* __restrict__ ssrt,
             const float* __restrict__ a_src, const float* __restrict__ a_dst,
             const float* __restrict__ m4, const float* __restrict__ inv4,
             const unsigned short* __restrict__ hb, const float* __restrict__ bias,
             unsigned short* __restrict__ ysb)
{
    __shared__ int   s_src[4][64];
    __shared__ float s_alp[4][64][4];
    const int lane = threadIdx.x & 63;
    const int wv = threadIdx.x >> 6;
    const int d = blockIdx.x * 4 + wv;
    if (d >= NND) return;
    const int beg = off[d];
    const int deg = off[d + 1] - beg;
    const float4 ad = *(const float4*)(a_dst + (size_t)d * 4);
    const float4 mm = *(const float4*)(m4 + (size_t)d * 4);
    const float4 iv = *(const float4*)(inv4 + (size_t)d * 4);

    const int cnt = min(deg, 64);
    if (lane < cnt) {
        const int s = ssrt[beg + lane];
        const float4 as = *(const float4*)(a_src + (size_t)s * 4);
        float4 al;
        al.x = __expf(leaky02(as.x + ad.x) - mm.x) * iv.x;
        al.y = __expf(leaky02(as.y + ad.y) - mm.y) * iv.y;
        al.z = __expf(leaky02(as.z + ad.z) - mm.z) * iv.z;
        al.w = __expf(leaky02(as.w + ad.w) - mm.w) * iv.w;
        s_src[wv][lane] = s;
        *(float4*)&s_alp[wv][lane][0] = al;
    }
    // wave-coherent LDS (same wave writes & reads; compiler inserts lgkmcnt)

    const int hsel = lane >> 4;               // head for channels 2*lane,2*lane+1
    float accx = 0.f, accy = 0.f;
    int k = 0;
    for (; k + 4 <= cnt; k += 4) {
        const int s0 = __builtin_amdgcn_readfirstlane(s_src[wv][k]);
        const int s1 = __builtin_amdgcn_readfirstlane(s_src[wv][k + 1]);
        const int s2 = __builtin_amdgcn_readfirstlane(s_src[wv][k + 2]);
        const int s3 = __builtin_amdgcn_readfirstlane(s_src[wv][k + 3]);
        const float A0 = s_alp[wv][k][hsel],     A1 = s_alp[wv][k + 1][hsel];
        const float A2 = s_alp[wv][k + 2][hsel], A3 = s_alp[wv][k + 3][hsel];
        const unsigned u0 = *(const unsigned*)(hb + (size_t)s0 * 128 + 2 * lane);
        const unsigned u1 = *(const unsigned*)(hb + (size_t)s1 * 128 + 2 * lane);
        const unsigned u2 = *(const unsigned*)(hb + (size_t)s2 * 128 + 2 * lane);
        const unsigned u3 = *(const unsigned*)(hb + (size_t)s3 * 128 + 2 * lane);
        accx += __uint_as_float(u0 << 16) * A0;
        accy += __uint_as_float(u0 & 0xffff0000u) * A0;
        accx += __uint_as_float(u1 << 16) * A1;
        accy += __uint_as_float(u1 & 0xffff0000u) * A1;
        accx += __uint_as_float(u2 << 16) * A2;
        accy += __uint_as_float(u2 & 0xffff0000u) * A2;
        accx += __uint_as_float(u3 << 16) * A3;
        accy += __uint_as_float(u3 & 0xffff0000u) * A3;
    }
    for (; k < cnt; ++k) {
        const int s = __builtin_amdgcn_readfirstlane(s_src[wv][k]);
        const float A = s_alp[wv][k][hsel];
        const unsigned u = *(const unsigned*)(hb + (size_t)s * 128 + 2 * lane);
        accx += __uint_as_float(u << 16) * A;
        accy += __uint_as_float(u & 0xffff0000u) * A;
    }
    // rare deg>64 chunks (no reductions needed: m/inv precomputed)
    for (int base = 64; base < deg; base += 64) {
        const int c2 = min(64, deg - base);
        if (lane < c2) {
            const int s = ssrt[beg + base + lane];
            const float4 as = *(const float4*)(a_src + (size_t)s * 4);
            float4 al2;
            al2.x = __expf(leaky02(as.x + ad.x) - mm.x) * iv.x;
            al2.y = __expf(leaky02(as.y + ad.y) - mm.y) * iv.y;
            al2.z = __expf(leaky02(as.z + ad.z) - mm.z) * iv.z;
            al2.w = __expf(leaky02(as.w + ad.w) - mm.w) * iv.w;
            s_src[wv][lane] = s;
            *(float4*)&s_alp[wv][lane][0] = al2;
        }
        for (int kk = 0; kk < c2; ++kk) {
            const int s = __builtin_amdgcn_readfirstlane(s_src[wv][kk]);
            const float A = s_alp[wv][kk][hsel];
            const unsigned u = *(const unsigned*)(hb + (size_t)s * 128 + 2 * lane);
            accx += __uint_as_float(u << 16) * A;
            accy += __uint_as_float(u & 0xffff0000u) * A;
        }
    }
    // fused bias + relu, bf16 pack (one dword store per lane)
    const float2 bb = *(const float2*)(bias + 2 * lane);
    float ox = accx + bb.x, oy = accy + bb.y;
    ox = ox > 0.f ? ox : 0.f;
    oy = oy > 0.f ? oy : 0.f;
    const unsigned up = (unsigned)f2bf(ox) | ((unsigned)f2bf(oy) << 16);
    *(unsigned*)(ysb + (size_t)d * 128 + 2 * lane) = up;
}

// ---------------------------------------------------------------------------
// K_out (MFMA): out = ys @ lin_w + lin_b  (N x 128 @ 128 x 64), bf16 inputs.
// Same structure as k_gemm1: 32 rows/block, 4 waves; wave wv owns cols
// [wv*16, wv*16+16); 2 row-tiles x 4 ks = 8 MFMA/wave.
// ---------------------------------------------------------------------------
__global__ __launch_bounds__(256)
void k_out(const unsigned short* __restrict__ ysb, const unsigned short* __restrict__ wf,
           const float* __restrict__ lin_b, float* __restrict__ out)
{
    __shared__ unsigned short yb[32 * 128];   // 8 KB, XOR-swizzled
    const int tid = threadIdx.x;
    const int wv = tid >> 6;
    const int l = tid & 63;
    const int lg = l >> 4;
    const int lc = l & 15;
    const int row0 = blockIdx.x * 32;   // 3125 blocks

    // stage ys rows (already bf16): 1024 uint2s, swizzled like gemm1
    const uint2* ysrc = (const uint2*)(ysb + (size_t)row0 * 128);
#pragma unroll
    for (int i = 0; i < 4; ++i) {
        const int g = tid + 256 * i;
        const int row = g >> 5;
        const int kq = g & 31;
        const uint2 v = ysrc[g];
        const int byteoff = (row * 256 + kq * 8) ^ ((row & 7) << 4);
        *(uint2*)((char*)yb + byteoff) = v;
    }

    short8 bf[4];
#pragma unroll
    for (int ks = 0; ks < 4; ++ks)
        bf[ks] = *(const short8*)(wf + (size_t)((2048 + (wv * 4 + ks) * 64 + l) * 8));

    __syncthreads();

    f32x4 acc[2];
    acc[0] = (f32x4){0.f, 0.f, 0.f, 0.f};
    acc[1] = (f32x4){0.f, 0.f, 0.f, 0.f};

#pragma unroll
    for (int ks = 0; ks < 4; ++ks) {
        short8 a[2];
#pragma unroll
        for (int rt = 0; rt < 2; ++rt) {
            const int row = rt * 16 + lc;
            const int byteoff = (row * 256 + (ks * 32 + lg * 8) * 2) ^ ((row & 7) << 4);
            a[rt] = *(const short8*)((const char*)yb + byteoff);
        }
#pragma unroll
        for (int rt = 0; rt < 2; ++rt)
            acc[rt] = __builtin_amdgcn_mfma_f32_16x16x32_bf16(a[rt], bf[ks], acc[rt], 0, 0, 0);
    }

    const int col = wv * 16 + lc;
    const float lb = lin_b[col];
#pragma unroll
    for (int rt = 0; rt < 2; ++rt) {
#pragma unroll
        for (int r = 0; r < 4; ++r) {
            const int row = row0 + rt * 16 + lg * 4 + r;
            out[(size_t)row * 64 + col] = acc[rt][r] + lb;
        }
    }
}

extern "C" void kernel_launch(void* const* d_in, const int* in_sizes, int n_in,
                              void* d_out, int out_size, void* d_ws, size_t ws_size,
                              hipStream_t stream)
{
    const float* x     = (const float*)d_in[0];
    const int*   ei    = (const int*)  d_in[1];   // [2][E] int32
    const float* W     = (const float*)d_in[2];
    const float* att_s = (const float*)d_in[3];
    const float* att_d = (const float*)d_in[4];
    const float* bias  = (const float*)d_in[5];
    const float* lin_w = (const float*)d_in[6];
    const float* lin_b = (const float*)d_in[7];
    float* out = (float*)d_out;

    const int* esrc = ei;        // edge_index[0] = message source
    const int* edst = ei + NED;  // edge_index[1] = message target

    char* ws = (char*)d_ws;
    unsigned short* hb  = (unsigned short*)(ws + OFF_HB);
    unsigned short* ysb = (unsigned short*)(ws + OFF_YS);
    float* a_src = (float*)(ws + OFF_ASRC);
    float* a_dst = (float*)(ws + OFF_ADST);
    int*   offs  = (int*)  (ws + OFF_OFFS);
    int*   cnts  = (int*)  (ws + OFF_CNT);
    int*   ssrt  = (int*)  (ws + OFF_SRT);
    int*   bsum  = (int*)  (ws + OFF_BSUM);
    int*   bpref = (int*)  (ws + OFF_BPREF);
    unsigned short* wf = (unsigned short*)(ws + OFF_WF);
    float* m4   = (float*)(ws + OFF_M4);
    float* inv4 = (float*)(ws + OFF_INV4);

    // CSR build (dst-sorted edge list, self-loop at each segment head)
    k_count_init<<<(NND + 255) / 256, 256, 0, stream>>>(cnts);
    k_hist<<<(NED + 255) / 256, 256, 0, stream>>>(edst, cnts);
    k_scan_partial<<<SCAN_NB, SCAN_BS, 0, stream>>>(cnts, bsum);
    k_scan_bsums<<<1, 512, 0, stream>>>(bsum, bpref);
    k_scan_final<<<SCAN_NB, SCAN_BS, 0, stream>>>(cnts, bpref, offs);
    k_count_init<<<(NND + 255) / 256, 256, 0, stream>>>(cnts);  // reset cursors
    k_scatter_rng<<<NRANGE * NCHUNK, 256, 0, stream>>>(esrc, edst, offs, cnts, ssrt);

    // weight fragments, feature transform + attention logits
    k_wprep<<<12, 256, 0, stream>>>(W, lin_w, wf);
    k_gemm1<<<NND / 32, 256, 0, stream>>>(x, wf, att_s, att_d, hb, a_src, a_dst);

    // per-node softmax stats (thread-serial, reduction-free)
    k_prep<<<(NND + 255) / 256, 256, 0, stream>>>(offs, ssrt, a_src, a_dst, m4, inv4);

    // fused alpha + aggregation + bias + relu (bf16 ys out)
    k_fused<<<(NND + 3) / 4, 256, 0, stream>>>(offs, ssrt, a_src, a_dst, m4, inv4,
                                               hb, bias, ysb);

    // output projection (MFMA)
    k_out<<<NND / 32, 256, 0, stream>>>(ysb, wf, lin_b, out);
}

// Round 11
// 280.794 us; speedup vs baseline: 1.0424x; 1.0424x over previous
//
#include <hip/hip_runtime.h>
#include <math.h>

// Problem constants (fixed by the reference file)
#define NND 100000            // nodes
#define NED 1600000           // edges (before self-loops)
#define TOTE (NND + NED)      // edges + self-loops

#define SCAN_BS 256
#define SCAN_NB ((NND + SCAN_BS - 1) / SCAN_BS)   // 391

// dst-range-partitioned scatter (one range per XCD)
#define NRANGE 8
#define RNG_NODES ((NND + NRANGE - 1) / NRANGE)   // 12500
#define NCHUNK 640
#define CHUNK_E ((NED + NCHUNK - 1) / NCHUNK)     // 2500

// Workspace layout (bytes), total ~104.5 MB (<= 113.2 MB proven in r2/r3)
#define OFF_HB    ((size_t)0)            // N*128 bf16 (h)
#define OFF_YS    ((size_t)25600000)     // N*128 bf16 (relu(agg+bias))
#define OFF_ASRC  ((size_t)76800000)
#define OFF_ADST  ((size_t)78400000)
#define OFF_OFFS  ((size_t)80000000)
#define OFF_CNT   ((size_t)80400016)
#define OFF_SRT   ((size_t)80800016)
#define OFF_BSUM  ((size_t)87600016)
#define OFF_BPREF ((size_t)87604016)
#define OFF_WF    ((size_t)87608016)     // 3072 frags * 8 ushort = 48 KB
#define OFF_M4    ((size_t)87657168)     // N*4 f32 (segment max)
#define OFF_INV4  ((size_t)89257168)     // N*4 f32 (1/denom)
#define OFF_ELOG  ((size_t)90857168)     // TOTE * 8 B (bf16x4 leaky logits)

typedef __attribute__((ext_vector_type(8))) short short8;
typedef __attribute__((ext_vector_type(4))) float f32x4;

__device__ __forceinline__ float leaky02(float v) { return v > 0.f ? v : 0.2f * v; }

// f32 -> bf16 with round-to-nearest-even
__device__ __forceinline__ unsigned short f2bf(float f) {
    unsigned u = __float_as_uint(f);
    return (unsigned short)((u + 0x7fffu + ((u >> 16) & 1u)) >> 16);
}

__device__ __forceinline__ uint2 pack4(float4 e) {
    uint2 u;
    u.x = (unsigned)f2bf(e.x) | ((unsigned)f2bf(e.y) << 16);
    u.y = (unsigned)f2bf(e.z) | ((unsigned)f2bf(e.w) << 16);
    return u;
}

__device__ __forceinline__ float4 unpack4(uint2 u) {
    float4 e;
    e.x = __uint_as_float(u.x << 16);
    e.y = __uint_as_float(u.x & 0xffff0000u);
    e.z = __uint_as_float(u.y << 16);
    e.w = __uint_as_float(u.y & 0xffff0000u);
    return e;
}

// ---------------------------------------------------------------------------
// CSR build (proven r6-r8, frozen)
// ---------------------------------------------------------------------------
__global__ __launch_bounds__(256)
void k_count_init(int* __restrict__ counts) {
    const int i = blockIdx.x * 256 + threadIdx.x;
    if (i < NND) counts[i] = 1;
}

__global__ __launch_bounds__(256)
void k_hist(const int* __restrict__ edst, int* __restrict__ counts) {
    const int e = blockIdx.x * 256 + threadIdx.x;
    if (e < NED) atomicAdd(&counts[edst[e]], 1);
}

__global__ __launch_bounds__(SCAN_BS)
void k_scan_partial(const int* __restrict__ counts, int* __restrict__ bsum) {
    __shared__ int s[SCAN_BS];
    const int t = threadIdx.x;
    const int i = blockIdx.x * SCAN_BS + t;
    s[t] = (i < NND) ? counts[i] : 0;
    __syncthreads();
#pragma unroll
    for (int d = SCAN_BS / 2; d > 0; d >>= 1) {
        if (t < d) s[t] += s[t + d];
        __syncthreads();
    }
    if (t == 0) bsum[blockIdx.x] = s[0];
}

__global__ __launch_bounds__(512)
void k_scan_bsums(const int* __restrict__ bsum, int* __restrict__ bpref) {
    __shared__ int s[512];
    const int t = threadIdx.x;
    const int v0 = (t < SCAN_NB) ? bsum[t] : 0;
    s[t] = v0;
    __syncthreads();
#pragma unroll
    for (int d = 1; d < 512; d <<= 1) {
        int v = (t >= d) ? s[t - d] : 0;
        __syncthreads();
        s[t] += v;
        __syncthreads();
    }
    if (t < SCAN_NB) bpref[t] = s[t] - v0;   // exclusive
}

__global__ __launch_bounds__(SCAN_BS)
void k_scan_final(const int* __restrict__ counts, const int* __restrict__ bpref,
                  int* __restrict__ off) {
    __shared__ int s[SCAN_BS];
    const int t = threadIdx.x;
    const int i = blockIdx.x * SCAN_BS + t;
    const int v0 = (i < NND) ? counts[i] : 0;
    s[t] = v0;
    __syncthreads();
#pragma unroll
    for (int d = 1; d < SCAN_BS; d <<= 1) {
        int v = (t >= d) ? s[t - d] : 0;
        __syncthreads();
        s[t] += v;
        __syncthreads();
    }
    if (i < NND) off[i + 1] = bpref[blockIdx.x] + s[t];
    if (i == 0) off[0] = 0;
}

// ---------------------------------------------------------------------------
// Range-partitioned scatter (r8 proven) + NEW: materialize per-edge leaky
// logits elog[pos] = bf16x4(leaky(a_src[s]+a_dst[d])). a_src/a_dst are 1.6MB
// each (L2-resident); elog writes share ssrt's single-XCD line locality.
// Downstream kernels then read edge data SEQUENTIALLY (no random a_src
// gathers left anywhere but the irreducible hb row gather).
// ---------------------------------------------------------------------------
__global__ __launch_bounds__(256)
void k_scatter_rng(const int* __restrict__ esrc, const int* __restrict__ edst,
                   const float* __restrict__ a_src, const float* __restrict__ a_dst,
                   const int* __restrict__ off, int* __restrict__ counts,
                   int* __restrict__ ssrt, uint2* __restrict__ elog)
{
    const int r = blockIdx.x % NRANGE;
    const int chunk = blockIdx.x / NRANGE;
    const int dlo = r * RNG_NODES;
    const int dhi = min(NND, dlo + RNG_NODES);

    if (chunk == 0) {   // self-loop at each segment head
        for (int d = dlo + threadIdx.x; d < dhi; d += 256) {
            const float4 as = *(const float4*)(a_src + (size_t)d * 4);
            const float4 ad = *(const float4*)(a_dst + (size_t)d * 4);
            float4 e4;
            e4.x = leaky02(as.x + ad.x);
            e4.y = leaky02(as.y + ad.y);
            e4.z = leaky02(as.z + ad.z);
            e4.w = leaky02(as.w + ad.w);
            const int pos = off[d];
            ssrt[pos] = d;
            elog[pos] = pack4(e4);
        }
    }
    const int elo = chunk * CHUNK_E;
    const int ehi = min(NED, elo + CHUNK_E);
    for (int e = elo + threadIdx.x; e < ehi; e += 256) {
        const int d = edst[e];
        if (d >= dlo && d < dhi) {
            const int s = esrc[e];
            const int pos = off[d] + atomicAdd(&counts[d], 1);
            const float4 as = *(const float4*)(a_src + (size_t)s * 4);
            const float4 ad = *(const float4*)(a_dst + (size_t)d * 4);
            float4 e4;
            e4.x = leaky02(as.x + ad.x);
            e4.y = leaky02(as.y + ad.y);
            e4.z = leaky02(as.z + ad.z);
            e4.w = leaky02(as.w + ad.w);
            ssrt[pos] = s;
            elog[pos] = pack4(e4);
        }
    }
}

// ---------------------------------------------------------------------------
// W pre-fragmentation (r9/r10 proven).
// ---------------------------------------------------------------------------
__global__ __launch_bounds__(256)
void k_wprep(const float* __restrict__ W, const float* __restrict__ lin_w,
             unsigned short* __restrict__ wf) {
    const int idx = blockIdx.x * 256 + threadIdx.x;
    if (idx < 2048) {
        const int l  = idx & 63;
        const int ks = (idx >> 6) & 3;
        const int ct = (idx >> 8) & 1;
        const int wv = idx >> 9;
        const int col = wv * 32 + ct * 16 + (l & 15);
        const int k0  = ks * 32 + (l >> 4) * 8;
#pragma unroll
        for (int j = 0; j < 8; ++j)
            wf[idx * 8 + j] = f2bf(W[(size_t)(k0 + j) * 128 + col]);
    } else if (idx < 3072) {
        const int i2 = idx - 2048;
        const int l  = i2 & 63;
        const int ks = (i2 >> 6) & 3;
        const int wv = i2 >> 8;
        const int col = wv * 16 + (l & 15);
        const int k0  = ks * 32 + (l >> 4) * 8;
#pragma unroll
        for (int j = 0; j < 8; ++j)
            wf[idx * 8 + j] = f2bf(lin_w[(size_t)(k0 + j) * 64 + col]);
    }
}

// ---------------------------------------------------------------------------
// K1 (MFMA): h = x @ W (bf16 out), fused a_src/a_dst epilogue. (r9 proven.)
// ---------------------------------------------------------------------------
__global__ __launch_bounds__(256)
void k_gemm1(const float* __restrict__ x, const unsigned short* __restrict__ wf,
             const float* __restrict__ att_s, const float* __restrict__ att_d,
             unsigned short* __restrict__ hb,
             float* __restrict__ a_src, float* __restrict__ a_dst)
{
    __shared__ unsigned short xb[32 * 128];   // 8 KB, XOR-swizzled
    const int tid = threadIdx.x;
    const int wv = tid >> 6;          // wave = head
    const int l = tid & 63;
    const int lg = l >> 4;
    const int lc = l & 15;
    const int row0 = blockIdx.x * 32;

    const float4* x4 = (const float4*)(x + (size_t)row0 * 128);
#pragma unroll
    for (int i = 0; i < 4; ++i) {
        const int g = tid + 256 * i;
        const int row = g >> 5;
        const int kq = g & 31;
        const float4 v = x4[g];
        uint2 p;
        p.x = (unsigned)f2bf(v.x) | ((unsigned)f2bf(v.y) << 16);
        p.y = (unsigned)f2bf(v.z) | ((unsigned)f2bf(v.w) << 16);
        const int byteoff = (row * 256 + kq * 8) ^ ((row & 7) << 4);
        *(uint2*)((char*)xb + byteoff) = p;
    }

    short8 bf[2][4];
#pragma unroll
    for (int ct = 0; ct < 2; ++ct)
#pragma unroll
        for (int ks = 0; ks < 4; ++ks)
            bf[ct][ks] = *(const short8*)(wf + (size_t)((((wv * 2 + ct) * 4 + ks) * 64 + l) * 8));

    __syncthreads();

    f32x4 acc[2][2];
#pragma unroll
    for (int rt = 0; rt < 2; ++rt)
#pragma unroll
        for (int ct = 0; ct < 2; ++ct)
            acc[rt][ct] = (f32x4){0.f, 0.f, 0.f, 0.f};

#pragma unroll
    for (int ks = 0; ks < 4; ++ks) {
        short8 a[2];
#pragma unroll
        for (int rt = 0; rt < 2; ++rt) {
            const int row = rt * 16 + lc;
            const int byteoff = (row * 256 + (ks * 32 + lg * 8) * 2) ^ ((row & 7) << 4);
            a[rt] = *(const short8*)((const char*)xb + byteoff);
        }
#pragma unroll
        for (int rt = 0; rt < 2; ++rt)
#pragma unroll
            for (int ct = 0; ct < 2; ++ct)
                acc[rt][ct] = __builtin_amdgcn_mfma_f32_16x16x32_bf16(
                    a[rt], bf[ct][ks], acc[rt][ct], 0, 0, 0);
    }

    const int c0 = wv * 32 + lc;
    const float as0 = att_s[c0], as1 = att_s[c0 + 16];
    const float ad0 = att_d[c0], ad1 = att_d[c0 + 16];

#pragma unroll
    for (int rt = 0; rt < 2; ++rt) {
#pragma unroll
        for (int r = 0; r < 4; ++r) {
            const int row = row0 + rt * 16 + lg * 4 + r;
            const float h0 = acc[rt][0][r];
            const float h1 = acc[rt][1][r];
            hb[(size_t)row * 128 + c0]      = f2bf(h0);
            hb[(size_t)row * 128 + c0 + 16] = f2bf(h1);
            float vs = h0 * as0 + h1 * as1;
            float vd = h0 * ad0 + h1 * ad1;
#pragma unroll
            for (int o = 8; o > 0; o >>= 1) {
                vs += __shfl_xor(vs, o, 64);
                vd += __shfl_xor(vd, o, 64);
            }
            if (lc == 0) {
                a_src[row * 4 + wv] = vs;
                a_dst[row * 4 + wv] = vd;
            }
        }
    }
}

// ---------------------------------------------------------------------------
// K_prep: per-node segment max + inv-denom from SEQUENTIAL elog reads (one
// thread per node; consecutive threads own consecutive segments -> coalesced
// streaming, no random gathers at all).
// ---------------------------------------------------------------------------
__global__ __launch_bounds__(256)
void k_prep(const int* __restrict__ off, const uint2* __restrict__ elog,
            float* __restrict__ m4, float* __restrict__ inv4)
{
    const int d = blockIdx.x * 256 + threadIdx.x;
    if (d >= NND) return;
    const int beg = off[d];
    const int end = off[d + 1];

    float4 mx = make_float4(-1e30f, -1e30f, -1e30f, -1e30f);
    for (int i = beg; i < end; ++i) {
        const float4 e = unpack4(elog[i]);
        mx.x = fmaxf(mx.x, e.x);
        mx.y = fmaxf(mx.y, e.y);
        mx.z = fmaxf(mx.z, e.z);
        mx.w = fmaxf(mx.w, e.w);
    }
    float4 sm = make_float4(0.f, 0.f, 0.f, 0.f);
    for (int i = beg; i < end; ++i) {
        const float4 e = unpack4(elog[i]);
        sm.x += __expf(e.x - mx.x);
        sm.y += __expf(e.y - mx.y);
        sm.z += __expf(e.z - mx.z);
        sm.w += __expf(e.w - mx.w);
    }
    *(float4*)(m4 + (size_t)d * 4) = mx;
    *(float4*)(inv4 + (size_t)d * 4) =
        make_float4(1.f / (sm.x + 1e-16f), 1.f / (sm.y + 1e-16f),
                    1.f / (sm.z + 1e-16f), 1.f / (sm.w + 1e-16f));
}

// ---------------------------------------------------------------------------
// K_fused: per-node wave; alphas from sequential elog (m/inv precomputed),
// staged in per-wave LDS; bf16 h gather with wave-uniform SGPR base; fused
// bias + relu, bf16 ys out. (r10 structure, a_src gather removed.)
// ---------------------------------------------------------------------------
__global__ __launch_bounds__(256)
void k_fused(const int* __restrict__ off, const int* __restrict__ ssrt,
             const uint2* __restrict__ elog,
             const float* __restrict__ m4, const float* __restrict__ inv4,
             const unsigned short* __restrict__ hb, const float* __restrict__ bias,
             unsigned short* __restrict__ ysb)
{
    __shared__ int   s_src[4][64];
    __shared__ float s_alp[4][64][4];
    const int lane = threadIdx.x & 63;
    const int wv = threadIdx.x >> 6;
    const int d = blockIdx.x * 4 + wv;
    if (d >= NND) return;
    const int beg = off[d];
    const int deg = off[d + 1] - beg;
    const float4 mm = *(const float4*)(m4 + (size_t)d * 4);
    const float4 iv = *(const float4*)(inv4 + (size_t)d * 4);

    const int cnt = min(deg, 64);
    if (lane < cnt) {
        const int s = ssrt[beg + lane];
        const float4 e = unpack4(elog[beg + lane]);
        float4 al;
        al.x = __expf(e.x - mm.x) * iv.x;
        al.y = __expf(e.y - mm.y) * iv.y;
        al.z = __expf(e.z - mm.z) * iv.z;
        al.w = __expf(e.w - mm.w) * iv.w;
        s_src[wv][lane] = s;
        *(float4*)&s_alp[wv][lane][0] = al;
    }
    // wave-coherent LDS (same wave writes & reads)

    const int hsel = lane >> 4;               // head for channels 2*lane,2*lane+1
    float accx = 0.f, accy = 0.f;
    int k = 0;
    for (; k + 4 <= cnt; k += 4) {
        const int s0 = __builtin_amdgcn_readfirstlane(s_src[wv][k]);
        const int s1 = __builtin_amdgcn_readfirstlane(s_src[wv][k + 1]);
        const int s2 = __builtin_amdgcn_readfirstlane(s_src[wv][k + 2]);
        const int s3 = __builtin_amdgcn_readfirstlane(s_src[wv][k + 3]);
        const float A0 = s_alp[wv][k][hsel],     A1 = s_alp[wv][k + 1][hsel];
        const float A2 = s_alp[wv][k + 2][hsel], A3 = s_alp[wv][k + 3][hsel];
        const unsigned u0 = *(const unsigned*)(hb + (size_t)s0 * 128 + 2 * lane);
        const unsigned u1 = *(const unsigned*)(hb + (size_t)s1 * 128 + 2 * lane);
        const unsigned u2 = *(const unsigned*)(hb + (size_t)s2 * 128 + 2 * lane);
        const unsigned u3 = *(const unsigned*)(hb + (size_t)s3 * 128 + 2 * lane);
        accx += __uint_as_float(u0 << 16) * A0;
        accy += __uint_as_float(u0 & 0xffff0000u) * A0;
        accx += __uint_as_float(u1 << 16) * A1;
        accy += __uint_as_float(u1 & 0xffff0000u) * A1;
        accx += __uint_as_float(u2 << 16) * A2;
        accy += __uint_as_float(u2 & 0xffff0000u) * A2;
        accx += __uint_as_float(u3 << 16) * A3;
        accy += __uint_as_float(u3 & 0xffff0000u) * A3;
    }
    for (; k < cnt; ++k) {
        const int s = __builtin_amdgcn_readfirstlane(s_src[wv][k]);
        const float A = s_alp[wv][k][hsel];
        const unsigned u = *(const unsigned*)(hb + (size_t)s * 128 + 2 * lane);
        accx += __uint_as_float(u << 16) * A;
        accy += __uint_as_float(u & 0xffff0000u) * A;
    }
    // rare deg>64 chunks
    for (int base = 64; base < deg; base += 64) {
        const int c2 = min(64, deg - base);
        if (lane < c2) {
            const int s = ssrt[beg + base + lane];
            const float4 e = unpack4(elog[beg + base + lane]);
            float4 al2;
            al2.x = __expf(e.x - mm.x) * iv.x;
            al2.y = __expf(e.y - mm.y) * iv.y;
            al2.z = __expf(e.z - mm.z) * iv.z;
            al2.w = __expf(e.w - mm.w) * iv.w;
            s_src[wv][lane] = s;
            *(float4*)&s_alp[wv][lane][0] = al2;
        }
        for (int kk = 0; kk < c2; ++kk) {
            const int s = __builtin_amdgcn_readfirstlane(s_src[wv][kk]);
            const float A = s_alp[wv][kk][hsel];
            const unsigned u = *(const unsigned*)(hb + (size_t)s * 128 + 2 * lane);
            accx += __uint_as_float(u << 16) * A;
            accy += __uint_as_float(u & 0xffff0000u) * A;
        }
    }
    // fused bias + relu, bf16 pack
    const float2 bb = *(const float2*)(bias + 2 * lane);
    float ox = accx + bb.x, oy = accy + bb.y;
    ox = ox > 0.f ? ox : 0.f;
    oy = oy > 0.f ? oy : 0.f;
    const unsigned up = (unsigned)f2bf(ox) | ((unsigned)f2bf(oy) << 16);
    *(unsigned*)(ysb + (size_t)d * 128 + 2 * lane) = up;
}

// ---------------------------------------------------------------------------
// K_out (MFMA): out = ys @ lin_w + lin_b, bf16 inputs. (r10 proven.)
// ---------------------------------------------------------------------------
__global__ __launch_bounds__(256)
void k_out(const unsigned short* __restrict__ ysb, const unsigned short* __restrict__ wf,
           const float* __restrict__ lin_b, float* __restrict__ out)
{
    __shared__ unsigned short yb[32 * 128];   // 8 KB, XOR-swizzled
    const int tid = threadIdx.x;
    const int wv = tid >> 6;
    const int l = tid & 63;
    const int lg = l >> 4;
    const int lc = l & 15;
    const int row0 = blockIdx.x * 32;

    const uint2* ysrc = (const uint2*)(ysb + (size_t)row0 * 128);
#pragma unroll
    for (int i = 0; i < 4; ++i) {
        const int g = tid + 256 * i;
        const int row = g >> 5;
        const int kq = g & 31;
        const uint2 v = ysrc[g];
        const int byteoff = (row * 256 + kq * 8) ^ ((row & 7) << 4);
        *(uint2*)((char*)yb + byteoff) = v;
    }

    short8 bf[4];
#pragma unroll
    for (int ks = 0; ks < 4; ++ks)
        bf[ks] = *(const short8*)(wf + (size_t)((2048 + (wv * 4 + ks) * 64 + l) * 8));

    __syncthreads();

    f32x4 acc[2];
    acc[0] = (f32x4){0.f, 0.f, 0.f, 0.f};
    acc[1] = (f32x4){0.f, 0.f, 0.f, 0.f};

#pragma unroll
    for (int ks = 0; ks < 4; ++ks) {
        short8 a[2];
#pragma unroll
        for (int rt = 0; rt < 2; ++rt) {
            const int row = rt * 16 + lc;
            const int byteoff = (row * 256 + (ks * 32 + lg * 8) * 2) ^ ((row & 7) << 4);
            a[rt] = *(const short8*)((const char*)yb + byteoff);
        }
#pragma unroll
        for (int rt = 0; rt < 2; ++rt)
            acc[rt] = __builtin_amdgcn_mfma_f32_16x16x32_bf16(a[rt], bf[ks], acc[rt], 0, 0, 0);
    }

    const int col = wv * 16 + lc;
    const float lb = lin_b[col];
#pragma unroll
    for (int rt = 0; rt < 2; ++rt) {
#pragma unroll
        for (int r = 0; r < 4; ++r) {
            const int row = row0 + rt * 16 + lg * 4 + r;
            out[(size_t)row * 64 + col] = acc[rt][r] + lb;
        }
    }
}

extern "C" void kernel_launch(void* const* d_in, const int* in_sizes, int n_in,
                              void* d_out, int out_size, void* d_ws, size_t ws_size,
                              hipStream_t stream)
{
    const float* x     = (const float*)d_in[0];
    const int*   ei    = (const int*)  d_in[1];   // [2][E] int32
    const float* W     = (const float*)d_in[2];
    const float* att_s = (const float*)d_in[3];
    const float* att_d = (const float*)d_in[4];
    const float* bias  = (const float*)d_in[5];
    const float* lin_w = (const float*)d_in[6];
    const float* lin_b = (const float*)d_in[7];
    float* out = (float*)d_out;

    const int* esrc = ei;        // edge_index[0] = message source
    const int* edst = ei + NED;  // edge_index[1] = message target

    char* ws = (char*)d_ws;
    unsigned short* hb  = (unsigned short*)(ws + OFF_HB);
    unsigned short* ysb = (unsigned short*)(ws + OFF_YS);
    float* a_src = (float*)(ws + OFF_ASRC);
    float* a_dst = (float*)(ws + OFF_ADST);
    int*   offs  = (int*)  (ws + OFF_OFFS);
    int*   cnts  = (int*)  (ws + OFF_CNT);
    int*   ssrt  = (int*)  (ws + OFF_SRT);
    int*   bsum  = (int*)  (ws + OFF_BSUM);
    int*   bpref = (int*)  (ws + OFF_BPREF);
    unsigned short* wf = (unsigned short*)(ws + OFF_WF);
    float* m4   = (float*)(ws + OFF_M4);
    float* inv4 = (float*)(ws + OFF_INV4);
    uint2* elog = (uint2*)(ws + OFF_ELOG);

    // CSR offsets (independent of gemm1)
    k_count_init<<<(NND + 255) / 256, 256, 0, stream>>>(cnts);
    k_hist<<<(NED + 255) / 256, 256, 0, stream>>>(edst, cnts);
    k_scan_partial<<<SCAN_NB, SCAN_BS, 0, stream>>>(cnts, bsum);
    k_scan_bsums<<<1, 512, 0, stream>>>(bsum, bpref);
    k_scan_final<<<SCAN_NB, SCAN_BS, 0, stream>>>(cnts, bpref, offs);
    k_count_init<<<(NND + 255) / 256, 256, 0, stream>>>(cnts);  // reset cursors

    // weight fragments + feature transform (produces a_src/a_dst for scatter)
    k_wprep<<<12, 256, 0, stream>>>(W, lin_w, wf);
    k_gemm1<<<NND / 32, 256, 0, stream>>>(x, wf, att_s, att_d, hb, a_src, a_dst);

    // scatter edges + materialize per-edge bf16 logits
    k_scatter_rng<<<NRANGE * NCHUNK, 256, 0, stream>>>(esrc, edst, a_src, a_dst,
                                                       offs, cnts, ssrt, elog);

    // per-node softmax stats (pure streaming now)
    k_prep<<<(NND + 255) / 256, 256, 0, stream>>>(offs, elog, m4, inv4);

    // fused alpha + aggregation + bias + relu (bf16 ys out)
    k_fused<<<(NND + 3) / 4, 256, 0, stream>>>(offs, ssrt, elog, m4, inv4,
                                               hb, bias, ysb);

    // output projection (MFMA)
    k_out<<<NND / 32, 256, 0, stream>>>(ysb, wf, lin_b, out);
}

// Round 12
// 280.194 us; speedup vs baseline: 1.0446x; 1.0021x over previous
//
#include <hip/hip_runtime.h>
#include <math.h>

// Problem constants (fixed by the reference file)
#define NND 100000            // nodes
#define NED 1600000           // edges (before self-loops)
#define TOTE (NND + NED)      // edges + self-loops

#define SCAN_BS 256
#define SCAN_NB ((NND + SCAN_BS - 1) / SCAN_BS)   // 391

// dst-range-partitioned scatter (one range per XCD)
#define NRANGE 8
#define RNG_NODES ((NND + NRANGE - 1) / NRANGE)   // 12500
#define NCHUNK 640
#define CHUNK_E ((NED + NCHUNK - 1) / NCHUNK)     // 2500

// Workspace layout (bytes), total ~104.5 MB (<= 113.2 MB proven in r2/r3)
#define OFF_HB    ((size_t)0)            // N*128 bf16 (h)
#define OFF_YS    ((size_t)25600000)     // N*128 bf16 (relu(agg+bias))
#define OFF_ASRC  ((size_t)76800000)
#define OFF_ADST  ((size_t)78400000)
#define OFF_OFFS  ((size_t)80000000)
#define OFF_CNT   ((size_t)80400016)
#define OFF_SRT   ((size_t)80800016)
#define OFF_BSUM  ((size_t)87600016)
#define OFF_BPREF ((size_t)87604016)
#define OFF_WF    ((size_t)87608016)     // 3072 frags * 8 ushort = 48 KB
#define OFF_M4    ((size_t)87657168)     // N*4 f32 (segment max)
#define OFF_INV4  ((size_t)89257168)     // N*4 f32 (1/denom)
#define OFF_ELOG  ((size_t)90857168)     // TOTE * 8 B (bf16x4 leaky logits)

typedef __attribute__((ext_vector_type(8))) short short8;
typedef __attribute__((ext_vector_type(4))) float f32x4;

__device__ __forceinline__ float leaky02(float v) { return v > 0.f ? v : 0.2f * v; }

// f32 -> bf16 with round-to-nearest-even
__device__ __forceinline__ unsigned short f2bf(float f) {
    unsigned u = __float_as_uint(f);
    return (unsigned short)((u + 0x7fffu + ((u >> 16) & 1u)) >> 16);
}

__device__ __forceinline__ uint2 pack4(float4 e) {
    uint2 u;
    u.x = (unsigned)f2bf(e.x) | ((unsigned)f2bf(e.y) << 16);
    u.y = (unsigned)f2bf(e.z) | ((unsigned)f2bf(e.w) << 16);
    return u;
}

__device__ __forceinline__ float4 unpack4(uint2 u) {
    float4 e;
    e.x = __uint_as_float(u.x << 16);
    e.y = __uint_as_float(u.x & 0xffff0000u);
    e.z = __uint_as_float(u.y << 16);
    e.w = __uint_as_float(u.y & 0xffff0000u);
    return e;
}

// ---------------------------------------------------------------------------
// CSR build (proven r6-r8, frozen)
// ---------------------------------------------------------------------------
__global__ __launch_bounds__(256)
void k_count_init(int* __restrict__ counts) {
    const int i = blockIdx.x * 256 + threadIdx.x;
    if (i < NND) counts[i] = 1;
}

__global__ __launch_bounds__(256)
void k_hist(const int* __restrict__ edst, int* __restrict__ counts) {
    const int e = blockIdx.x * 256 + threadIdx.x;
    if (e < NED) atomicAdd(&counts[edst[e]], 1);
}

__global__ __launch_bounds__(SCAN_BS)
void k_scan_partial(const int* __restrict__ counts, int* __restrict__ bsum) {
    __shared__ int s[SCAN_BS];
    const int t = threadIdx.x;
    const int i = blockIdx.x * SCAN_BS + t;
    s[t] = (i < NND) ? counts[i] : 0;
    __syncthreads();
#pragma unroll
    for (int d = SCAN_BS / 2; d > 0; d >>= 1) {
        if (t < d) s[t] += s[t + d];
        __syncthreads();
    }
    if (t == 0) bsum[blockIdx.x] = s[0];
}

__global__ __launch_bounds__(512)
void k_scan_bsums(const int* __restrict__ bsum, int* __restrict__ bpref) {
    __shared__ int s[512];
    const int t = threadIdx.x;
    const int v0 = (t < SCAN_NB) ? bsum[t] : 0;
    s[t] = v0;
    __syncthreads();
#pragma unroll
    for (int d = 1; d < 512; d <<= 1) {
        int v = (t >= d) ? s[t - d] : 0;
        __syncthreads();
        s[t] += v;
        __syncthreads();
    }
    if (t < SCAN_NB) bpref[t] = s[t] - v0;   // exclusive
}

__global__ __launch_bounds__(SCAN_BS)
void k_scan_final(const int* __restrict__ counts, const int* __restrict__ bpref,
                  int* __restrict__ off) {
    __shared__ int s[SCAN_BS];
    const int t = threadIdx.x;
    const int i = blockIdx.x * SCAN_BS + t;
    const int v0 = (i < NND) ? counts[i] : 0;
    s[t] = v0;
    __syncthreads();
#pragma unroll
    for (int d = 1; d < SCAN_BS; d <<= 1) {
        int v = (t >= d) ? s[t - d] : 0;
        __syncthreads();
        s[t] += v;
        __syncthreads();
    }
    if (i < NND) off[i + 1] = bpref[blockIdx.x] + s[t];
    if (i == 0) off[0] = 0;
}

// ---------------------------------------------------------------------------
// Range-partitioned scatter (r8 proven) + NEW: materialize per-edge leaky
// logits elog[pos] = bf16x4(leaky(a_src[s]+a_dst[d])). a_src/a_dst are 1.6MB
// each (L2-resident); elog writes share ssrt's single-XCD line locality.
// Downstream kernels then read edge data SEQUENTIALLY (no random a_src
// gathers left anywhere but the irreducible hb row gather).
// ---------------------------------------------------------------------------
__global__ __launch_bounds__(256)
void k_scatter_rng(const int* __restrict__ esrc, const int* __restrict__ edst,
                   const float* __restrict__ a_src, const float* __restrict__ a_dst,
                   const int* __restrict__ off, int* __restrict__ counts,
                   int* __restrict__ ssrt, uint2* __restrict__ elog)
{
    const int r = blockIdx.x % NRANGE;
    const int chunk = blockIdx.x / NRANGE;
    const int dlo = r * RNG_NODES;
    const int dhi = min(NND, dlo + RNG_NODES);

    if (chunk == 0) {   // self-loop at each segment head
        for (int d = dlo + threadIdx.x; d < dhi; d += 256) {
            const float4 as = *(const float4*)(a_src + (size_t)d * 4);
            const float4 ad = *(const float4*)(a_dst + (size_t)d * 4);
            float4 e4;
            e4.x = leaky02(as.x + ad.x);
            e4.y = leaky02(as.y + ad.y);
            e4.z = leaky02(as.z + ad.z);
            e4.w = leaky02(as.w + ad.w);
            const int pos = off[d];
            ssrt[pos] = d;
            elog[pos] = pack4(e4);
        }
    }
    const int elo = chunk * CHUNK_E;
    const int ehi = min(NED, elo + CHUNK_E);
    for (int e = elo + threadIdx.x; e < ehi; e += 256) {
        const int d = edst[e];
        if (d >= dlo && d < dhi) {
            const int s = esrc[e];
            const int pos = off[d] + atomicAdd(&counts[d], 1);
            const float4 as = *(const float4*)(a_src + (size_t)s * 4);
            const float4 ad = *(const float4*)(a_dst + (size_t)d * 4);
            float4 e4;
            e4.x = leaky02(as.x + ad.x);
            e4.y = leaky02(as.y + ad.y);
            e4.z = leaky02(as.z + ad.z);
            e4.w = leaky02(as.w + ad.w);
            ssrt[pos] = s;
            elog[pos] = pack4(e4);
        }
    }
}

// ---------------------------------------------------------------------------
// W pre-fragmentation (r9/r10 proven).
// ---------------------------------------------------------------------------
__global__ __launch_bounds__(256)
void k_wprep(const float* __restrict__ W, const float* __restrict__ lin_w,
             unsigned short* __restrict__ wf) {
    const int idx = blockIdx.x * 256 + threadIdx.x;
    if (idx < 2048) {
        const int l  = idx & 63;
        const int ks = (idx >> 6) & 3;
        const int ct = (idx >> 8) & 1;
        const int wv = idx >> 9;
        const int col = wv * 32 + ct * 16 + (l & 15);
        const int k0  = ks * 32 + (l >> 4) * 8;
#pragma unroll
        for (int j = 0; j < 8; ++j)
            wf[idx * 8 + j] = f2bf(W[(size_t)(k0 + j) * 128 + col]);
    } else if (idx < 3072) {
        const int i2 = idx - 2048;
        const int l  = i2 & 63;
        const int ks = (i2 >> 6) & 3;
        const int wv = i2 >> 8;
        const int col = wv * 16 + (l & 15);
        const int k0  = ks * 32 + (l >> 4) * 8;
#pragma unroll
        for (int j = 0; j < 8; ++j)
            wf[idx * 8 + j] = f2bf(lin_w[(size_t)(k0 + j) * 64 + col]);
    }
}

// ---------------------------------------------------------------------------
// K1 (MFMA): h = x @ W (bf16 out), fused a_src/a_dst epilogue. (r9 proven.)
// ---------------------------------------------------------------------------
__global__ __launch_bounds__(256)
void k_gemm1(const float* __restrict__ x, const unsigned short* __restrict__ wf,
             const float* __restrict__ att_s, const float* __restrict__ att_d,
             unsigned short* __restrict__ hb,
             float* __restrict__ a_src, float* __restrict__ a_dst)
{
    __shared__ unsigned short xb[32 * 128];   // 8 KB, XOR-swizzled
    const int tid = threadIdx.x;
    const int wv = tid >> 6;          // wave = head
    const int l = tid & 63;
    const int lg = l >> 4;
    const int lc = l & 15;
    const int row0 = blockIdx.x * 32;

    const float4* x4 = (const float4*)(x + (size_t)row0 * 128);
#pragma unroll
    for (int i = 0; i < 4; ++i) {
        const int g = tid + 256 * i;
        const int row = g >> 5;
        const int kq = g & 31;
        const float4 v = x4[g];
        uint2 p;
        p.x = (unsigned)f2bf(v.x) | ((unsigned)f2bf(v.y) << 16);
        p.y = (unsigned)f2bf(v.z) | ((unsigned)f2bf(v.w) << 16);
        const int byteoff = (row * 256 + kq * 8) ^ ((row & 7) << 4);
        *(uint2*)((char*)xb + byteoff) = p;
    }

    short8 bf[2][4];
#pragma unroll
    for (int ct = 0; ct < 2; ++ct)
#pragma unroll
        for (int ks = 0; ks < 4; ++ks)
            bf[ct][ks] = *(const short8*)(wf + (size_t)((((wv * 2 + ct) * 4 + ks) * 64 + l) * 8));

    __syncthreads();

    f32x4 acc[2][2];
#pragma unroll
    for (int rt = 0; rt < 2; ++rt)
#pragma unroll
        for (int ct = 0; ct < 2; ++ct)
            acc[rt][ct] = (f32x4){0.f, 0.f, 0.f, 0.f};

#pragma unroll
    for (int ks = 0; ks < 4; ++ks) {
        short8 a[2];
#pragma unroll
        for (int rt = 0; rt < 2; ++rt) {
            const int row = rt * 16 + lc;
            const int byteoff = (row * 256 + (ks * 32 + lg * 8) * 2) ^ ((row & 7) << 4);
            a[rt] = *(const short8*)((const char*)xb + byteoff);
        }
#pragma unroll
        for (int rt = 0; rt < 2; ++rt)
#pragma unroll
            for (int ct = 0; ct < 2; ++ct)
                acc[rt][ct] = __builtin_amdgcn_mfma_f32_16x16x32_bf16(
                    a[rt], bf[ct][ks], acc[rt][ct], 0, 0, 0);
    }

    const int c0 = wv * 32 + lc;
    const float as0 = att_s[c0], as1 = att_s[c0 + 16];
    const float ad0 = att_d[c0], ad1 = att_d[c0 + 16];

#pragma unroll
    for (int rt = 0; rt < 2; ++rt) {
#pragma unroll
        for (int r = 0; r < 4; ++r) {
            const int row = row0 + rt * 16 + lg * 4 + r;
            const float h0 = acc[rt][0][r];
            const float h1 = acc[rt][1][r];
            hb[(size_t)row * 128 + c0]      = f2bf(h0);
            hb[(size_t)row * 128 + c0 + 16] = f2bf(h1);
            float vs = h0 * as0 + h1 * as1;
            float vd = h0 * ad0 + h1 * ad1;
#pragma unroll
            for (int o = 8; o > 0; o >>= 1) {
                vs += __shfl_xor(vs, o, 64);
                vd += __shfl_xor(vd, o, 64);
            }
            if (lc == 0) {
                a_src[row * 4 + wv] = vs;
                a_dst[row * 4 + wv] = vd;
            }
        }
    }
}

// ---------------------------------------------------------------------------
// K_prep: per-node segment max + inv-denom from SEQUENTIAL elog reads (one
// thread per node; consecutive threads own consecutive segments -> coalesced
// streaming, no random gathers at all).
// ---------------------------------------------------------------------------
__global__ __launch_bounds__(256)
void k_prep(const int* __restrict__ off, const uint2* __restrict__ elog,
            float* __restrict__ m4, float* __restrict__ inv4)
{
    const int d = blockIdx.x * 256 + threadIdx.x;
    if (d >= NND) return;
    const int beg = off[d];
    const int end = off[d + 1];

    float4 mx = make_float4(-1e30f, -1e30f, -1e30f, -1e30f);
    for (int i = beg; i < end; ++i) {
        const float4 e = unpack4(elog[i]);
        mx.x = fmaxf(mx.x, e.x);
        mx.y = fmaxf(mx.y, e.y);
        mx.z = fmaxf(mx.z, e.z);
        mx.w = fmaxf(mx.w, e.w);
    }
    float4 sm = make_float4(0.f, 0.f, 0.f, 0.f);
    for (int i = beg; i < end; ++i) {
        const float4 e = unpack4(elog[i]);
        sm.x += __expf(e.x - mx.x);
        sm.y += __expf(e.y - mx.y);
        sm.z += __expf(e.z - mx.z);
        sm.w += __expf(e.w - mx.w);
    }
    *(float4*)(m4 + (size_t)d * 4) = mx;
    *(float4*)(inv4 + (size_t)d * 4) =
        make_float4(1.f / (sm.x + 1e-16f), 1.f / (sm.y + 1e-16f),
                    1.f / (sm.z + 1e-16f), 1.f / (sm.w + 1e-16f));
}

// ---------------------------------------------------------------------------
// K_fused: per-node wave; alphas from sequential elog (m/inv precomputed),
// staged in per-wave LDS; bf16 h gather with wave-uniform SGPR base; fused
// bias + relu, bf16 ys out. (r10 structure, a_src gather removed.)
// ---------------------------------------------------------------------------
__global__ __launch_bounds__(256)
void k_fused(const int* __restrict__ off, const int* __restrict__ ssrt,
             const uint2* __restrict__ elog,
             const float* __restrict__ m4, const float* __restrict__ inv4,
             const unsigned short* __restrict__ hb, const float* __restrict__ bias,
             unsigned short* __restrict__ ysb)
{
    __shared__ int   s_src[4][64];
    __shared__ float s_alp[4][64][4];
    const int lane = threadIdx.x & 63;
    const int wv = threadIdx.x >> 6;
    const int d = blockIdx.x * 4 + wv;
    if (d >= NND) return;
    const int beg = off[d];
    const int deg = off[d + 1] - beg;
    const float4 mm = *(const float4*)(m4 + (size_t)d * 4);
    const float4 iv = *(const float4*)(inv4 + (size_t)d * 4);

    const int cnt = min(deg, 64);
    if (lane < cnt) {
        const int s = ssrt[beg + lane];
        const float4 e = unpack4(elog[beg + lane]);
        float4 al;
        al.x = __expf(e.x - mm.x) * iv.x;
        al.y = __expf(e.y - mm.y) * iv.y;
        al.z = __expf(e.z - mm.z) * iv.z;
        al.w = __expf(e.w - mm.w) * iv.w;
        s_src[wv][lane] = s;
        *(float4*)&s_alp[wv][lane][0] = al;
    }
    // wave-coherent LDS (same wave writes & reads)

    const int hsel = lane >> 4;               // head for channels 2*lane,2*lane+1
    float accx = 0.f, accy = 0.f;
    int k = 0;
    for (; k + 4 <= cnt; k += 4) {
        const int s0 = __builtin_amdgcn_readfirstlane(s_src[wv][k]);
        const int s1 = __builtin_amdgcn_readfirstlane(s_src[wv][k + 1]);
        const int s2 = __builtin_amdgcn_readfirstlane(s_src[wv][k + 2]);
        const int s3 = __builtin_amdgcn_readfirstlane(s_src[wv][k + 3]);
        const float A0 = s_alp[wv][k][hsel],     A1 = s_alp[wv][k + 1][hsel];
        const float A2 = s_alp[wv][k + 2][hsel], A3 = s_alp[wv][k + 3][hsel];
        const unsigned u0 = *(const unsigned*)(hb + (size_t)s0 * 128 + 2 * lane);
        const unsigned u1 = *(const unsigned*)(hb + (size_t)s1 * 128 + 2 * lane);
        const unsigned u2 = *(const unsigned*)(hb + (size_t)s2 * 128 + 2 * lane);
        const unsigned u3 = *(const unsigned*)(hb + (size_t)s3 * 128 + 2 * lane);
        accx += __uint_as_float(u0 << 16) * A0;
        accy += __uint_as_float(u0 & 0xffff0000u) * A0;
        accx += __uint_as_float(u1 << 16) * A1;
        accy += __uint_as_float(u1 & 0xffff0000u) * A1;
        accx += __uint_as_float(u2 << 16) * A2;
        accy += __uint_as_float(u2 & 0xffff0000u) * A2;
        accx += __uint_as_float(u3 << 16) * A3;
        accy += __uint_as_float(u3 & 0xffff0000u) * A3;
    }
    for (; k < cnt; ++k) {
        const int s = __builtin_amdgcn_readfirstlane(s_src[wv][k]);
        const float A = s_alp[wv][k][hsel];
        const unsigned u = *(const unsigned*)(hb + (size_t)s * 128 + 2 * lane);
        accx += __uint_as_float(u << 16) * A;
        accy += __uint_as_float(u & 0xffff0000u) * A;
    }
    // rare deg>64 chunks
    for (int base = 64; base < deg; base += 64) {
        const int c2 = min(64, deg - base);
        if (lane < c2) {
            const int s = ssrt[beg + base + lane];
            const float4 e = unpack4(elog[beg + base + lane]);
            float4 al2;
            al2.x = __expf(e.x - mm.x) * iv.x;
            al2.y = __expf(e.y - mm.y) * iv.y;
            al2.z = __expf(e.z - mm.z) * iv.z;
            al2.w = __expf(e.w - mm.w) * iv.w;
            s_src[wv][lane] = s;
            *(float4*)&s_alp[wv][lane][0] = al2;
        }
        for (int kk = 0; kk < c2; ++kk) {
            const int s = __builtin_amdgcn_readfirstlane(s_src[wv][kk]);
            const float A = s_alp[wv][kk][hsel];
            const unsigned u = *(const unsigned*)(hb + (size_t)s * 128 + 2 * lane);
            accx += __uint_as_float(u << 16) * A;
            accy += __uint_as_float(u & 0xffff0000u) * A;
        }
    }
    // fused bias + relu, bf16 pack
    const float2 bb = *(const float2*)(bias + 2 * lane);
    float ox = accx + bb.x, oy = accy + bb.y;
    ox = ox > 0.f ? ox : 0.f;
    oy = oy > 0.f ? oy : 0.f;
    const unsigned up = (unsigned)f2bf(ox) | ((unsigned)f2bf(oy) << 16);
    *(unsigned*)(ysb + (size_t)d * 128 + 2 * lane) = up;
}

// ---------------------------------------------------------------------------
// K_out (MFMA): out = ys @ lin_w + lin_b, bf16 inputs. (r10 proven.)
// ---------------------------------------------------------------------------
__global__ __launch_bounds__(256)
void k_out(const unsigned short* __restrict__ ysb, const unsigned short* __restrict__ wf,
           const float* __restrict__ lin_b, float* __restrict__ out)
{
    __shared__ unsigned short yb[32 * 128];   // 8 KB, XOR-swizzled
    const int tid = threadIdx.x;
    const int wv = tid >> 6;
    const int l = tid & 63;
    const int lg = l >> 4;
    const int lc = l & 15;
    const int row0 = blockIdx.x * 32;

    const uint2* ysrc = (const uint2*)(ysb + (size_t)row0 * 128);
#pragma unroll
    for (int i = 0; i < 4; ++i) {
        const int g = tid + 256 * i;
        const int row = g >> 5;
        const int kq = g & 31;
        const uint2 v = ysrc[g];
        const int byteoff = (row * 256 + kq * 8) ^ ((row & 7) << 4);
        *(uint2*)((char*)yb + byteoff) = v;
    }

    short8 bf[4];
#pragma unroll
    for (int ks = 0; ks < 4; ++ks)
        bf[ks] = *(const short8*)(wf + (size_t)((2048 + (wv * 4 + ks) * 64 + l) * 8));

    __syncthreads();

    f32x4 acc[2];
    acc[0] = (f32x4){0.f, 0.f, 0.f, 0.f};
    acc[1] = (f32x4){0.f, 0.f, 0.f, 0.f};

#pragma unroll
    for (int ks = 0; ks < 4; ++ks) {
        short8 a[2];
#pragma unroll
        for (int rt = 0; rt < 2; ++rt) {
            const int row = rt * 16 + lc;
            const int byteoff = (row * 256 + (ks * 32 + lg * 8) * 2) ^ ((row & 7) << 4);
            a[rt] = *(const short8*)((const char*)yb + byteoff);
        }
#pragma unroll
        for (int rt = 0; rt < 2; ++rt)
            acc[rt] = __builtin_amdgcn_mfma_f32_16x16x32_bf16(a[rt], bf[ks], acc[rt], 0, 0, 0);
    }

    const int col = wv * 16 + lc;
    const float lb = lin_b[col];
#pragma unroll
    for (int rt = 0; rt < 2; ++rt) {
#pragma unroll
        for (int r = 0; r < 4; ++r) {
            const int row = row0 + rt * 16 + lg * 4 + r;
            out[(size_t)row * 64 + col] = acc[rt][r] + lb;
        }
    }
}

extern "C" void kernel_launch(void* const* d_in, const int* in_sizes, int n_in,
                              void* d_out, int out_size, void* d_ws, size_t ws_size,
                              hipStream_t stream)
{
    const float* x     = (const float*)d_in[0];
    const int*   ei    = (const int*)  d_in[1];   // [2][E] int32
    const float* W     = (const float*)d_in[2];
    const float* att_s = (const float*)d_in[3];
    const float* att_d = (const float*)d_in[4];
    const float* bias  = (const float*)d_in[5];
    const float* lin_w = (const float*)d_in[6];
    const float* lin_b = (const float*)d_in[7];
    float* out = (float*)d_out;

    const int* esrc = ei;        // edge_index[0] = message source
    const int* edst = ei + NED;  // edge_index[1] = message target

    char* ws = (char*)d_ws;
    unsigned short* hb  = (unsigned short*)(ws + OFF_HB);
    unsigned short* ysb = (unsigned short*)(ws + OFF_YS);
    float* a_src = (float*)(ws + OFF_ASRC);
    float* a_dst = (float*)(ws + OFF_ADST);
    int*   offs  = (int*)  (ws + OFF_OFFS);
    int*   cnts  = (int*)  (ws + OFF_CNT);
    int*   ssrt  = (int*)  (ws + OFF_SRT);
    int*   bsum  = (int*)  (ws + OFF_BSUM);
    int*   bpref = (int*)  (ws + OFF_BPREF);
    unsigned short* wf = (unsigned short*)(ws + OFF_WF);
    float* m4   = (float*)(ws + OFF_M4);
    float* inv4 = (float*)(ws + OFF_INV4);
    uint2* elog = (uint2*)(ws + OFF_ELOG);

    // CSR offsets (independent of gemm1)
    k_count_init<<<(NND + 255) / 256, 256, 0, stream>>>(cnts);
    k_hist<<<(NED + 255) / 256, 256, 0, stream>>>(edst, cnts);
    k_scan_partial<<<SCAN_NB, SCAN_BS, 0, stream>>>(cnts, bsum);
    k_scan_bsums<<<1, 512, 0, stream>>>(bsum, bpref);
    k_scan_final<<<SCAN_NB, SCAN_BS, 0, stream>>>(cnts, bpref, offs);
    k_count_init<<<(NND + 255) / 256, 256, 0, stream>>>(cnts);  // reset cursors

    // weight fragments + feature transform (produces a_src/a_dst for scatter)
    k_wprep<<<12, 256, 0, stream>>>(W, lin_w, wf);
    k_gemm1<<<NND / 32, 256, 0, stream>>>(x, wf, att_s, att_d, hb, a_src, a_dst);

    // scatter edges + materialize per-edge bf16 logits
    k_scatter_rng<<<NRANGE * NCHUNK, 256, 0, stream>>>(esrc, edst, a_src, a_dst,
                                                       offs, cnts, ssrt, elog);

    // per-node softmax stats (pure streaming now)
    k_prep<<<(NND + 255) / 256, 256, 0, stream>>>(offs, elog, m4, inv4);

    // fused alpha + aggregation + bias + relu (bf16 ys out)
    k_fused<<<(NND + 3) / 4, 256, 0, stream>>>(offs, ssrt, elog, m4, inv4,
                                               hb, bias, ysb);

    // output projection (MFMA)
    k_out<<<NND / 32, 256, 0, stream>>>(ysb, wf, lin_b, out);
}